// Round 16
// baseline (84.096 us; speedup 1.0000x reference)
//
#include <hip/hip_runtime.h>
#include <hip/hip_bf16.h>

typedef float    f4    __attribute__((ext_vector_type(4)));
typedef short    s8v   __attribute__((ext_vector_type(8)));
typedef __bf16   bf8v  __attribute__((ext_vector_type(8)));
typedef unsigned int u32x4v __attribute__((ext_vector_type(4)));
typedef unsigned short u16;

#define NB 8
#define NN 256
#define ND 128

static __device__ __forceinline__ u16 f2bf(float f) {
    union { float f; unsigned u; } v; v.f = f;
    unsigned r = v.u + 0x7FFF + ((v.u >> 16) & 1);   // RNE
    return (u16)(r >> 16);
}

// pack two f32 -> two bf16 (round-half-up via +0x8000, then v_perm pack)
static __device__ __forceinline__ unsigned pack2bf(float a, float b) {
    unsigned ua = __builtin_bit_cast(unsigned, a) + 0x8000u;
    unsigned ub = __builtin_bit_cast(unsigned, b) + 0x8000u;
    return __builtin_amdgcn_perm(ub, ua, 0x07060302u);
}

// ---------------- precompute: P = x@W1a + b1m, Qn[b*256+j][d] = (x@W1b)[d], pack W1c
__global__ __launch_bounds__(256) void prep_kernel(
    const float* __restrict__ x, const float* __restrict__ W1m,
    const float* __restrict__ b1m,
    float* __restrict__ P, float* __restrict__ Qn, u16* __restrict__ W1cp)
{
    if (blockIdx.x == 1024) {
        // pack W1c (rows 256..383 of W1m) into MFMA B-fragment order
        for (int idx = threadIdx.x; idx < 16384; idx += 256) {
            int e  = idx & 7;
            int ln = (idx >> 3) & 63;
            int nt = (idx >> 9) & 7;
            int kt = idx >> 12;
            int k  = kt * 32 + (ln >> 4) * 8 + e;
            int d  = nt * 16 + (ln & 15);
            W1cp[idx] = f2bf(W1m[(2 * ND + k) * ND + d]);
        }
        return;
    }
    __shared__ float xl[256];
    int t = threadIdx.x;
    int row0 = blockIdx.x * 2;
    xl[t] = x[row0 * ND + t];
    __syncthreads();
    int r = t >> 7;
    int d = t & 127;
    int row = row0 + r;
    float sp = b1m[d], sq = 0.f;
    const float* xr = &xl[r * ND];
    #pragma unroll 8
    for (int k = 0; k < ND; ++k) {
        float xv = xr[k];
        sp += xv * W1m[k * ND + d];
        sq += xv * W1m[(ND + k) * ND + d];
    }
    P[row * ND + d] = sp;
    Qn[row * ND + d] = sq;          // row-major: coalesced reads in fused kernel
}

// ---------------- fused: per-block (b,i). 16 chunks x 16 rows.
// R9 structure (82us champion family) at 6 blocks/CU: reg-staged bf16
// (global f4 -> pack2bf -> ds_write_b128), 3 x 4KB buffers, depth-2 E
// register pipeline, ONE barrier per chunk, exact in-order vmcnt ledger.
// Q loaded transiently in-iteration (minimal persistent VGPR for bound 6).
__global__ __launch_bounds__(256, 6) void fused_kernel(
    const float* __restrict__ x, const float* __restrict__ edge0,
    const int* __restrict__ mask,
    const float* __restrict__ W2m, const float* __restrict__ b2m,
    const float* __restrict__ W1u, const float* __restrict__ b1u,
    const float* __restrict__ W2u, const float* __restrict__ b2u,
    const float* __restrict__ gamma, const float* __restrict__ beta,
    const float* __restrict__ P, const float* __restrict__ Qn,
    const u16* __restrict__ W1cp,
    float* __restrict__ out)
{
    __shared__ float ebuf[3][1024];   // 3 x 4KB bf16 chunk buffers (16 rows x 128 bf16)
    __shared__ float ml[NN];
    __shared__ float xrow[ND];
    __shared__ float redc[4], redA[4], redB[4];

    // tail scratch carved from ebuf[1] (last read of buf1: chunk 13)
    float* aggH = &ebuf[1][0];
    float* am   = &ebuf[1][128];
    float* hu   = &ebuf[1][256];
    float* yl   = &ebuf[1][384];

    // bijective XCD swizzle: XCD k owns batch k
    const int bid  = (blockIdx.x & 7) * 256 + (blockIdx.x >> 3);
    const int b    = bid >> 8;
    const int tid  = threadIdx.x;
    const int wave = tid >> 6;
    const int lane = tid & 63;
    const int l15  = lane & 15;
    const int lg   = lane >> 4;

    const char* e0c = (const char*)(edge0 + (size_t)bid * (NN * ND));

    float mval = (float)mask[bid * NN + tid];
    ml[tid] = mval;
    if (tid < ND) xrow[tid] = x[bid * ND + tid];

    // B fragments: this wave's 2 col-tiles x 4 k-tiles (32 VGPR)
    s8v bfr[4][2];
    #pragma unroll
    for (int kt = 0; kt < 4; ++kt)
        #pragma unroll
        for (int n = 0; n < 2; ++n)
            bfr[kt][n] = *reinterpret_cast<const s8v*>(
                &W1cp[(((kt * 8) + (wave * 2 + n)) * 64 + lane) * 8]);

    const int col0 = wave * 32 + l15;
    const float pv0 = P[bid * ND + col0];
    const float pv1 = P[bid * ND + col0 + 16];
    // Qn row base for this lane: row j = c*16 + lg*4 + r, element col0 (+16)
    const float* qbase = Qn + ((size_t)b * NN + lg * 4) * ND + col0;

    // staging geometry: thread t owns 8 consecutive f32 of the chunk
    const int srow  = tid >> 4;
    const int swoff = srow * 256 + (((tid & 15) * 16) ^ ((srow & 7) << 4));

    auto LOADE = [&](int cc, f4* er) {
        const char* cb = e0c + (size_t)cc * 8192 + tid * 32;
        er[0] = *reinterpret_cast<const f4*>(cb);
        er[1] = *reinterpret_cast<const f4*>(cb + 16);
    };
    auto WRITEE = [&](const f4* er, int bb) {
        u32x4v aw;
        aw[0] = pack2bf(er[0][0], er[0][1]);
        aw[1] = pack2bf(er[0][2], er[0][3]);
        aw[2] = pack2bf(er[1][0], er[1][1]);
        aw[3] = pack2bf(er[1][2], er[1][3]);
        *reinterpret_cast<u32x4v*>(
            reinterpret_cast<char*>(&ebuf[bb][0]) + swoff) = aw;
    };

    float agg0 = 0.f, agg1 = 0.f;
    f4 eA[2], eB[2];   // two static generations (even chunks -> eA, odd -> eB)

    // prologue: issue E0, E1; drain E0 (+ all older prologue VMEM); stage chunk0
    LOADE(0, eA);
    __builtin_amdgcn_sched_barrier(0);
    LOADE(1, eB);
    __builtin_amdgcn_sched_barrier(0);
    asm volatile("s_waitcnt vmcnt(2)" ::: "memory");   // E0 done, E1 in flight
    WRITEE(eA, 0);
    asm volatile("s_waitcnt lgkmcnt(0)" ::: "memory");

    #pragma unroll
    for (int c = 0; c < 16; ++c) {
        // top barrier: chunk c's LDS writes visible to all waves
        __builtin_amdgcn_s_barrier();
        __builtin_amdgcn_sched_barrier(0);
        // issue Q_c (transient) FIRST, then E_{c+2}: consuming Q leaves the
        // deep E prefetch in flight (in-order vmcnt).
        float q0v[4], q1v[4];
        {
            const float* qr = qbase + (size_t)c * 16 * ND;
            #pragma unroll
            for (int r = 0; r < 4; ++r) {
                q0v[r] = qr[r * ND];
                q1v[r] = qr[r * ND + 16];
            }
        }
        __builtin_amdgcn_sched_barrier(0);
        if (c < 14) {
            if (c & 1) LOADE(c + 2, eA); else LOADE(c + 2, eB);
            __builtin_amdgcn_sched_barrier(0);
        }
        // ---- compute chunk c from bf16 buf[c%3] ----
        const char* bufc = (const char*)&ebuf[c % 3][0];
        const int rb  = l15 * 256;
        const int swz = (l15 & 7) << 4;
        f4 acc0 = {0.f, 0.f, 0.f, 0.f};
        f4 acc1 = {0.f, 0.f, 0.f, 0.f};
        #pragma unroll
        for (int kt = 0; kt < 4; ++kt) {
            s8v av = *reinterpret_cast<const s8v*>(
                bufc + rb + ((kt * 64 + lg * 16) ^ swz));
            acc0 = __builtin_amdgcn_mfma_f32_16x16x32_bf16(
                __builtin_bit_cast(bf8v, av), __builtin_bit_cast(bf8v, bfr[kt][0]), acc0, 0, 0, 0);
            acc1 = __builtin_amdgcn_mfma_f32_16x16x32_bf16(
                __builtin_bit_cast(bf8v, av), __builtin_bit_cast(bf8v, bfr[kt][1]), acc1, 0, 0, 0);
        }
        // rows j = c*16 + lg*4 + r; mask + P + Q + relu + agg
        // (q-use wait drains E_{c+1} too — by design; E_{c+2} stays in flight)
        f4 mk = *reinterpret_cast<const f4*>(&ml[c * 16 + lg * 4]);
        #pragma unroll
        for (int r = 0; r < 4; ++r) {
            float h0 = fmaxf(acc0[r] + pv0 + q0v[r], 0.f);
            float h1 = fmaxf(acc1[r] + pv1 + q1v[r], 0.f);
            agg0 += mk[r] * h0;
            agg1 += mk[r] * h1;
        }
        __builtin_amdgcn_sched_barrier(0);
        // ---- stage chunk c+1 into buf (c+1)%3 (E_{c+1} drained by Q_c's wait) ----
        if (c < 15) {
            asm volatile("s_waitcnt vmcnt(2)" ::: "memory");  // E_{c+1}; leaves E_{c+2}
            if (c & 1) WRITEE(eA, (c + 1) % 3); else WRITEE(eB, (c + 1) % 3);
            asm volatile("s_waitcnt lgkmcnt(0)" ::: "memory");
            __builtin_amdgcn_sched_barrier(0);
        }
    }

    // reduce agg partials across the 4 row-groups
    agg0 += __shfl_xor(agg0, 16); agg0 += __shfl_xor(agg0, 32);
    agg1 += __shfl_xor(agg1, 16); agg1 += __shfl_xor(agg1, 32);
    // cnt = sum(mask)
    float cv = mval;
    #pragma unroll
    for (int o = 32; o > 0; o >>= 1) cv += __shfl_xor(cv, o);
    if (lane == 0) redc[wave] = cv;
    __syncthreads();   // main loop fully done; tail carve of ebuf[1] now safe
    if (lg == 0) {
        aggH[wave * 32 + l15]      = agg0;
        aggH[wave * 32 + 16 + l15] = agg1;
    }
    __syncthreads();

    const float cnt = redc[0] + redc[1] + redc[2] + redc[3];
    const float inv = 1.f / (cnt + 1e-6f);
    const int d  = tid & 127;
    const int hf = tid >> 7;

    // agg_msg = (aggH @ W2m + cnt*b2m) / (cnt+eps)
    {
        float s = 0.f;
        #pragma unroll 8
        for (int k = hf * 64; k < hf * 64 + 64; ++k) s += aggH[k] * W2m[k * ND + d];
        ml[tid] = s;
    }
    __syncthreads();
    if (tid < ND) am[d] = (ml[d] + ml[d + ND] + cnt * b2m[d]) * inv;
    __syncthreads();
    // hu = relu([x, agg] @ W1u + b1u)
    {
        float s = 0.f;
        const float* W = W1u + (size_t)hf * ND * ND;
        const float* v = hf ? am : xrow;
        #pragma unroll 8
        for (int k = 0; k < ND; ++k) s += v[k] * W[k * ND + d];
        ml[tid] = s;
    }
    __syncthreads();
    if (tid < ND) hu[d] = fmaxf(ml[d] + ml[d + ND] + b1u[d], 0.f);
    __syncthreads();
    // y = x + hu @ W2u + b2u
    {
        float s = 0.f;
        #pragma unroll 8
        for (int k = hf * 64; k < hf * 64 + 64; ++k) s += hu[k] * W2u[k * ND + d];
        ml[tid] = s;
    }
    __syncthreads();
    if (tid < ND) yl[d] = xrow[d] + ml[d] + ml[d + ND] + b2u[d];
    __syncthreads();
    // LayerNorm
    float yv = (tid < ND) ? yl[tid] : 0.f;
    float s1 = yv, s2 = yv * yv;
    #pragma unroll
    for (int o = 32; o > 0; o >>= 1) { s1 += __shfl_xor(s1, o); s2 += __shfl_xor(s2, o); }
    if (lane == 0) { redA[wave] = s1; redB[wave] = s2; }
    __syncthreads();
    if (tid < ND) {
        float mu  = (redA[0] + redA[1] + redA[2] + redA[3]) * (1.f / 128.f);
        float ex2 = (redB[0] + redB[1] + redB[2] + redB[3]) * (1.f / 128.f);
        float var = ex2 - mu * mu;
        float rs  = rsqrtf(var + 1e-5f);
        out[bid * ND + d] = (yl[d] - mu) * rs * gamma[d] + beta[d];
    }
}

extern "C" void kernel_launch(void* const* d_in, const int* in_sizes, int n_in,
                              void* d_out, int out_size, void* d_ws, size_t ws_size,
                              hipStream_t stream) {
    (void)in_sizes; (void)n_in; (void)out_size; (void)ws_size;
    const float* x     = (const float*)d_in[0];
    const float* edge0 = (const float*)d_in[1];
    const int*   mask  = (const int*)d_in[2];
    const float* W1m   = (const float*)d_in[3];
    const float* b1m   = (const float*)d_in[4];
    const float* W2m   = (const float*)d_in[5];
    const float* b2m   = (const float*)d_in[6];
    const float* W1u   = (const float*)d_in[7];
    const float* b1u   = (const float*)d_in[8];
    const float* W2u   = (const float*)d_in[9];
    const float* b2u   = (const float*)d_in[10];
    const float* gamma = (const float*)d_in[11];
    const float* beta  = (const float*)d_in[12];

    float* P    = (float*)d_ws;                 // 2048*128 f32 = 1 MB
    float* Qn   = P + 2048 * 128;               // 2048*128 f32 = 1 MB (row-major)
    u16*   W1cp = (u16*)(Qn + 2048 * 128);      // 16384 bf16 = 32 KB

    float* o = (float*)d_out;

    prep_kernel<<<dim3(1025), dim3(256), 0, stream>>>(x, W1m, b1m, P, Qn, W1cp);
    fused_kernel<<<dim3(2048), dim3(256), 0, stream>>>(
        x, edge0, mask, W2m, b2m, W1u, b1u, W2u, b2u, gamma, beta,
        P, Qn, W1cp, o);
}

// Round 17
// 81.257 us; speedup vs baseline: 1.0349x; 1.0349x over previous
//
#include <hip/hip_runtime.h>
#include <hip/hip_bf16.h>

typedef float    f4    __attribute__((ext_vector_type(4)));
typedef short    s8v   __attribute__((ext_vector_type(8)));
typedef __bf16   bf8v  __attribute__((ext_vector_type(8)));
typedef unsigned int u32x4v __attribute__((ext_vector_type(4)));
typedef unsigned short u16;

#define NB 8
#define NN 256
#define ND 128

static __device__ __forceinline__ u16 f2bf(float f) {
    union { float f; unsigned u; } v; v.f = f;
    unsigned r = v.u + 0x7FFF + ((v.u >> 16) & 1);   // RNE
    return (u16)(r >> 16);
}

// pack two f32 -> two bf16 (round-half-up via +0x8000, then v_perm pack)
static __device__ __forceinline__ unsigned pack2bf(float a, float b) {
    unsigned ua = __builtin_bit_cast(unsigned, a) + 0x8000u;
    unsigned ub = __builtin_bit_cast(unsigned, b) + 0x8000u;
    return __builtin_amdgcn_perm(ub, ua, 0x07060302u);
}

// ---------------- precompute: P = x@W1a + b1m, Qn[b*256+j][d] = (x@W1b)[d], pack W1c
__global__ __launch_bounds__(256) void prep_kernel(
    const float* __restrict__ x, const float* __restrict__ W1m,
    const float* __restrict__ b1m,
    float* __restrict__ P, float* __restrict__ Qn, u16* __restrict__ W1cp)
{
    if (blockIdx.x == 1024) {
        // pack W1c (rows 256..383 of W1m) into MFMA B-fragment order
        for (int idx = threadIdx.x; idx < 16384; idx += 256) {
            int e  = idx & 7;
            int ln = (idx >> 3) & 63;
            int nt = (idx >> 9) & 7;
            int kt = idx >> 12;
            int k  = kt * 32 + (ln >> 4) * 8 + e;
            int d  = nt * 16 + (ln & 15);
            W1cp[idx] = f2bf(W1m[(2 * ND + k) * ND + d]);
        }
        return;
    }
    __shared__ float xl[256];
    int t = threadIdx.x;
    int row0 = blockIdx.x * 2;
    xl[t] = x[row0 * ND + t];
    __syncthreads();
    int r = t >> 7;
    int d = t & 127;
    int row = row0 + r;
    float sp = b1m[d], sq = 0.f;
    const float* xr = &xl[r * ND];
    #pragma unroll 8
    for (int k = 0; k < ND; ++k) {
        float xv = xr[k];
        sp += xv * W1m[k * ND + d];
        sq += xv * W1m[(ND + k) * ND + d];
    }
    P[row * ND + d] = sp;
    Qn[row * ND + d] = sq;          // row-major: coalesced reads in fused kernel
}

// ---------------- fused: per-block (b,i). 16 chunks x 16 rows.
// CHAMPION (R15, 80.5us): reg-staged bf16 (global f4 -> pack2bf ->
// ds_write_b128), 3 x 4KB buffers, depth-2 E register pipeline + 1-iter-ahead
// Q register prefetch, ONE barrier per chunk, exact in-order vmcnt ledger,
// 5 blocks/CU, XCD-bijective swizzle.
__global__ __launch_bounds__(256, 5) void fused_kernel(
    const float* __restrict__ x, const float* __restrict__ edge0,
    const int* __restrict__ mask,
    const float* __restrict__ W2m, const float* __restrict__ b2m,
    const float* __restrict__ W1u, const float* __restrict__ b1u,
    const float* __restrict__ W2u, const float* __restrict__ b2u,
    const float* __restrict__ gamma, const float* __restrict__ beta,
    const float* __restrict__ P, const float* __restrict__ Qn,
    const u16* __restrict__ W1cp,
    float* __restrict__ out)
{
    __shared__ float ebuf[3][1024];   // 3 x 4KB bf16 chunk buffers (16 rows x 128 bf16)
    __shared__ float ml[NN];
    __shared__ float xrow[ND];
    __shared__ float redc[4], redA[4], redB[4];

    // tail scratch carved from ebuf[1] (last read of buf1: chunk 13)
    float* aggH = &ebuf[1][0];
    float* am   = &ebuf[1][128];
    float* hu   = &ebuf[1][256];
    float* yl   = &ebuf[1][384];

    // bijective XCD swizzle: XCD k owns batch k
    const int bid  = (blockIdx.x & 7) * 256 + (blockIdx.x >> 3);
    const int b    = bid >> 8;
    const int tid  = threadIdx.x;
    const int wave = tid >> 6;
    const int lane = tid & 63;
    const int l15  = lane & 15;
    const int lg   = lane >> 4;

    const char* e0c = (const char*)(edge0 + (size_t)bid * (NN * ND));

    float mval = (float)mask[bid * NN + tid];
    ml[tid] = mval;
    if (tid < ND) xrow[tid] = x[bid * ND + tid];

    // B fragments: this wave's 2 col-tiles x 4 k-tiles (32 VGPR)
    s8v bfr[4][2];
    #pragma unroll
    for (int kt = 0; kt < 4; ++kt)
        #pragma unroll
        for (int n = 0; n < 2; ++n)
            bfr[kt][n] = *reinterpret_cast<const s8v*>(
                &W1cp[(((kt * 8) + (wave * 2 + n)) * 64 + lane) * 8]);

    const int col0 = wave * 32 + l15;
    const float pv0 = P[bid * ND + col0];
    const float pv1 = P[bid * ND + col0 + 16];
    // Qn row base for this lane: row j = c*16 + lg*4 + r, element col0 (+16)
    const float* qbase = Qn + ((size_t)b * NN + lg * 4) * ND + col0;

    // staging geometry: thread t owns 8 consecutive f32 of the chunk
    const int srow  = tid >> 4;
    const int swoff = srow * 256 + (((tid & 15) * 16) ^ ((srow & 7) << 4));

    auto LOADE = [&](int cc, f4* er) {
        const char* cb = e0c + (size_t)cc * 8192 + tid * 32;
        er[0] = *reinterpret_cast<const f4*>(cb);
        er[1] = *reinterpret_cast<const f4*>(cb + 16);
    };
    auto WRITEE = [&](const f4* er, int bb) {
        u32x4v aw;
        aw[0] = pack2bf(er[0][0], er[0][1]);
        aw[1] = pack2bf(er[0][2], er[0][3]);
        aw[2] = pack2bf(er[1][0], er[1][1]);
        aw[3] = pack2bf(er[1][2], er[1][3]);
        *reinterpret_cast<u32x4v*>(
            reinterpret_cast<char*>(&ebuf[bb][0]) + swoff) = aw;
    };

    float agg0 = 0.f, agg1 = 0.f;
    f4 eA[2], eB[2];              // two E generations (even chunks -> eA, odd -> eB)
    float qg[2][2][4];            // two Q generations x {col0, col0+16} x 4 rows

    auto LOADQ = [&](int cc, int gen) {
        const float* qr = qbase + (size_t)cc * 16 * ND;
        #pragma unroll
        for (int r = 0; r < 4; ++r) {
            qg[gen][0][r] = qr[r * ND];
            qg[gen][1][r] = qr[r * ND + 16];
        }
    };

    // prologue: Q_0 (8 dwords), E_0 (2), E_1 (2); drain through E_0; stage chunk 0
    LOADQ(0, 0);
    __builtin_amdgcn_sched_barrier(0);
    LOADE(0, eA);
    __builtin_amdgcn_sched_barrier(0);
    LOADE(1, eB);
    __builtin_amdgcn_sched_barrier(0);
    asm volatile("s_waitcnt vmcnt(2)" ::: "memory");   // E_0 + Q_0 + older done; E_1 in flight
    WRITEE(eA, 0);
    asm volatile("s_waitcnt lgkmcnt(0)" ::: "memory");

    #pragma unroll
    for (int c = 0; c < 16; ++c) {
        // top barrier: chunk c's LDS writes visible to all waves
        __builtin_amdgcn_s_barrier();
        __builtin_amdgcn_sched_barrier(0);
        // issue Q_{c+1} (prefetch, consumed next iter) BEFORE E_{c+2}
        if (c < 15) {
            LOADQ(c + 1, (c + 1) & 1);
            __builtin_amdgcn_sched_barrier(0);
        }
        if (c < 14) {
            if (c & 1) LOADE(c + 2, eA); else LOADE(c + 2, eB);
            __builtin_amdgcn_sched_barrier(0);
        }
        // ---- compute chunk c from bf16 buf[c%3]; Q_c already in registers ----
        const char* bufc = (const char*)&ebuf[c % 3][0];
        const int rb  = l15 * 256;
        const int swz = (l15 & 7) << 4;
        f4 acc0 = {0.f, 0.f, 0.f, 0.f};
        f4 acc1 = {0.f, 0.f, 0.f, 0.f};
        #pragma unroll
        for (int kt = 0; kt < 4; ++kt) {
            s8v av = *reinterpret_cast<const s8v*>(
                bufc + rb + ((kt * 64 + lg * 16) ^ swz));
            acc0 = __builtin_amdgcn_mfma_f32_16x16x32_bf16(
                __builtin_bit_cast(bf8v, av), __builtin_bit_cast(bf8v, bfr[kt][0]), acc0, 0, 0, 0);
            acc1 = __builtin_amdgcn_mfma_f32_16x16x32_bf16(
                __builtin_bit_cast(bf8v, av), __builtin_bit_cast(bf8v, bfr[kt][1]), acc1, 0, 0, 0);
        }
        // rows j = c*16 + lg*4 + r; mask + P + Q(reg) + relu + agg — no load wait
        f4 mk = *reinterpret_cast<const f4*>(&ml[c * 16 + lg * 4]);
        const int g = c & 1;
        #pragma unroll
        for (int r = 0; r < 4; ++r) {
            float h0 = fmaxf(acc0[r] + pv0 + qg[g][0][r], 0.f);
            float h1 = fmaxf(acc1[r] + pv1 + qg[g][1][r], 0.f);
            agg0 += mk[r] * h0;
            agg1 += mk[r] * h1;
        }
        __builtin_amdgcn_sched_barrier(0);
        // ---- stage chunk c+1 into buf (c+1)%3 ----
        // queue (oldest->newest): E_{c+1}(2), Q_{c+1}(8), E_{c+2}(2)
        if (c < 15) {
            if (c < 14)
                asm volatile("s_waitcnt vmcnt(10)" ::: "memory"); // drain exactly E_{c+1}
            else
                asm volatile("s_waitcnt vmcnt(8)" ::: "memory");  // c=14: no E_16 issued
            if (c & 1) WRITEE(eA, (c + 1) % 3); else WRITEE(eB, (c + 1) % 3);
            asm volatile("s_waitcnt lgkmcnt(0)" ::: "memory");
            __builtin_amdgcn_sched_barrier(0);
        }
    }

    // reduce agg partials across the 4 row-groups
    agg0 += __shfl_xor(agg0, 16); agg0 += __shfl_xor(agg0, 32);
    agg1 += __shfl_xor(agg1, 16); agg1 += __shfl_xor(agg1, 32);
    // cnt = sum(mask)
    float cv = mval;
    #pragma unroll
    for (int o = 32; o > 0; o >>= 1) cv += __shfl_xor(cv, o);
    if (lane == 0) redc[wave] = cv;
    __syncthreads();   // main loop fully done; tail carve of ebuf[1] now safe
    if (lg == 0) {
        aggH[wave * 32 + l15]      = agg0;
        aggH[wave * 32 + 16 + l15] = agg1;
    }
    __syncthreads();

    const float cnt = redc[0] + redc[1] + redc[2] + redc[3];
    const float inv = 1.f / (cnt + 1e-6f);
    const int d  = tid & 127;
    const int hf = tid >> 7;

    // agg_msg = (aggH @ W2m + cnt*b2m) / (cnt+eps)
    {
        float s = 0.f;
        #pragma unroll 8
        for (int k = hf * 64; k < hf * 64 + 64; ++k) s += aggH[k] * W2m[k * ND + d];
        ml[tid] = s;
    }
    __syncthreads();
    if (tid < ND) am[d] = (ml[d] + ml[d + ND] + cnt * b2m[d]) * inv;
    __syncthreads();
    // hu = relu([x, agg] @ W1u + b1u)
    {
        float s = 0.f;
        const float* W = W1u + (size_t)hf * ND * ND;
        const float* v = hf ? am : xrow;
        #pragma unroll 8
        for (int k = 0; k < ND; ++k) s += v[k] * W[k * ND + d];
        ml[tid] = s;
    }
    __syncthreads();
    if (tid < ND) hu[d] = fmaxf(ml[d] + ml[d + ND] + b1u[d], 0.f);
    __syncthreads();
    // y = x + hu @ W2u + b2u
    {
        float s = 0.f;
        #pragma unroll 8
        for (int k = hf * 64; k < hf * 64 + 64; ++k) s += hu[k] * W2u[k * ND + d];
        ml[tid] = s;
    }
    __syncthreads();
    if (tid < ND) yl[d] = xrow[d] + ml[d] + ml[d + ND] + b2u[d];
    __syncthreads();
    // LayerNorm
    float yv = (tid < ND) ? yl[tid] : 0.f;
    float s1 = yv, s2 = yv * yv;
    #pragma unroll
    for (int o = 32; o > 0; o >>= 1) { s1 += __shfl_xor(s1, o); s2 += __shfl_xor(s2, o); }
    if (lane == 0) { redA[wave] = s1; redB[wave] = s2; }
    __syncthreads();
    if (tid < ND) {
        float mu  = (redA[0] + redA[1] + redA[2] + redA[3]) * (1.f / 128.f);
        float ex2 = (redB[0] + redB[1] + redB[2] + redB[3]) * (1.f / 128.f);
        float var = ex2 - mu * mu;
        float rs  = rsqrtf(var + 1e-5f);
        out[bid * ND + d] = (yl[d] - mu) * rs * gamma[d] + beta[d];
    }
}

extern "C" void kernel_launch(void* const* d_in, const int* in_sizes, int n_in,
                              void* d_out, int out_size, void* d_ws, size_t ws_size,
                              hipStream_t stream) {
    (void)in_sizes; (void)n_in; (void)out_size; (void)ws_size;
    const float* x     = (const float*)d_in[0];
    const float* edge0 = (const float*)d_in[1];
    const int*   mask  = (const int*)d_in[2];
    const float* W1m   = (const float*)d_in[3];
    const float* b1m   = (const float*)d_in[4];
    const float* W2m   = (const float*)d_in[5];
    const float* b2m   = (const float*)d_in[6];
    const float* W1u   = (const float*)d_in[7];
    const float* b1u   = (const float*)d_in[8];
    const float* W2u   = (const float*)d_in[9];
    const float* b2u   = (const float*)d_in[10];
    const float* gamma = (const float*)d_in[11];
    const float* beta  = (const float*)d_in[12];

    float* P    = (float*)d_ws;                 // 2048*128 f32 = 1 MB
    float* Qn   = P + 2048 * 128;               // 2048*128 f32 = 1 MB (row-major)
    u16*   W1cp = (u16*)(Qn + 2048 * 128);      // 16384 bf16 = 32 KB

    float* o = (float*)d_out;

    prep_kernel<<<dim3(1025), dim3(256), 0, stream>>>(x, W1m, b1m, P, Qn, W1cp);
    fused_kernel<<<dim3(2048), dim3(256), 0, stream>>>(
        x, edge0, mask, W2m, b2m, W1u, b1u, W2u, b2u, gamma, beta,
        P, Qn, W1cp, o);
}